// Round 1
// baseline (874.339 us; speedup 1.0000x reference)
//
#include <hip/hip_runtime.h>
#include <hip/hip_bf16.h>
#include <math.h>

#define B 64
#define L 400
#define IN_DIM 500
#define D 128
#define H 8
#define HD 16
#define NCONV 4
#define BL (B*L)

// ---------------------------------------------------------------------------
// Kernel 1: init conv (k=5, pad=2, 500->128) + bias + positional encoding
// Block: 128 threads (one per output channel d), tile of 16 l-positions.
// LDS: 20 rows x 500 floats = 40 KB. Grid: B * 25 = 1600.
// ---------------------------------------------------------------------------
__global__ __launch_bounds__(128) void k_initconv(
        const float* __restrict__ x, const float* __restrict__ w,
        const float* __restrict__ bias, float* __restrict__ out) {
    __shared__ float xs[20 * IN_DIM];
    const int tid = threadIdx.x;
    const int blk = blockIdx.x;
    const int b  = blk / 25;
    const int l0 = (blk - b * 25) * 16;

    // cooperative load of x[b, l0-2 .. l0+17, :] with zero padding (float4)
    for (int idx = tid; idx < 20 * 125; idx += 128) {
        int r  = idx / 125;
        int c4 = idx - r * 125;
        int gl = l0 - 2 + r;
        float4 v = make_float4(0.f, 0.f, 0.f, 0.f);
        if (gl >= 0 && gl < L)
            v = *(const float4*)(x + ((size_t)b * L + gl) * IN_DIM + c4 * 4);
        *(float4*)(xs + r * IN_DIM + c4 * 4) = v;
    }
    __syncthreads();

    const int d = tid;
    float acc[16];
#pragma unroll
    for (int j = 0; j < 16; ++j) acc[j] = 0.f;

    for (int c4 = 0; c4 < 125; ++c4) {
        float4 xr[20];
#pragma unroll
        for (int r = 0; r < 20; ++r)
            xr[r] = *(const float4*)(xs + r * IN_DIM + c4 * 4);
#pragma unroll
        for (int t = 0; t < 5; ++t) {
#pragma unroll
            for (int cc = 0; cc < 4; ++cc) {
                float wv = w[((size_t)(t * IN_DIM + c4 * 4 + cc)) * D + d];
#pragma unroll
                for (int j = 0; j < 16; ++j) {
                    const float* xp = (const float*)&xr[j + t];
                    acc[j] = fmaf(xp[cc], wv, acc[j]);
                }
            }
        }
    }

    // epilogue: + bias + posenc
    const float bsv = bias[d];
    const float pbase = expf(-(float)(d & ~1) * (9.210340371976184f / 128.0f));
#pragma unroll
    for (int j = 0; j < 16; ++j) {
        int l = l0 + j;
        float ang = (float)l * pbase;
        float pe = (d & 1) ? cosf(ang) : sinf(ang);
        out[((size_t)b * L + l) * D + d] = acc[j] + bsv + pe;
    }
}

// ---------------------------------------------------------------------------
// Kernel 2: LayerNorm over last dim (128). One wave per row, 4 rows/block.
// Grid: BL/4 = 6400, block 256.
// ---------------------------------------------------------------------------
__global__ __launch_bounds__(256) void k_ln(
        const float* __restrict__ in, const float* __restrict__ g,
        const float* __restrict__ bta, float* __restrict__ out) {
    int wave = threadIdx.x >> 6, lane = threadIdx.x & 63;
    size_t row = (size_t)blockIdx.x * 4 + wave;
    const float* p = in + row * D;
    float2 v = *(const float2*)(p + lane * 2);
    float s = v.x + v.y;
    float q = v.x * v.x + v.y * v.y;
#pragma unroll
    for (int off = 32; off; off >>= 1) {
        s += __shfl_xor(s, off);
        q += __shfl_xor(q, off);
    }
    float mu  = s * (1.f / 128.f);
    float var = q * (1.f / 128.f) - mu * mu;
    float inv = rsqrtf(var + 1e-5f);
    float2 gg = *(const float2*)(g + lane * 2);
    float2 bb = *(const float2*)(bta + lane * 2);
    float2 o;
    o.x = (v.x - mu) * inv * gg.x + bb.x;
    o.y = (v.y - mu) * inv * gg.y + bb.y;
    *(float2*)(out + row * D + lane * 2) = o;
}

// ---------------------------------------------------------------------------
// Kernel 3: depthwise conv k=7 pad=3 + bias. Tile 16 l x 128 d per block.
// Grid: B*25 = 1600, block 256. LDS 22x128 floats.
// ---------------------------------------------------------------------------
__global__ __launch_bounds__(256) void k_dw(
        const float* __restrict__ in, const float* __restrict__ w,
        const float* __restrict__ bias, float* __restrict__ out) {
    __shared__ float s[22 * D];
    int tid = threadIdx.x;
    int b  = blockIdx.x / 25;
    int l0 = (blockIdx.x - b * 25) * 16;
    for (int idx = tid; idx < 22 * D; idx += 256) {
        int r = idx >> 7, d = idx & 127;
        int gl = l0 - 3 + r;
        s[idx] = (gl >= 0 && gl < L) ? in[((size_t)b * L + gl) * D + d] : 0.f;
    }
    __syncthreads();
    int d = tid & 127, half = tid >> 7;
    float wr[7];
#pragma unroll
    for (int t = 0; t < 7; ++t) wr[t] = w[t * D + d];
    float bs = bias[d];
    for (int jj = 0; jj < 8; ++jj) {
        int lj = half * 8 + jj;
        float a = bs;
#pragma unroll
        for (int t = 0; t < 7; ++t) a = fmaf(s[(lj + t) * D + d], wr[t], a);
        out[((size_t)b * L + l0 + lj) * D + d] = a;
    }
}

// ---------------------------------------------------------------------------
// Kernel 4: generic [BL,128] x [128,128] GEMM, fused bias / relu / residual.
// Block tile 64m x 128n, thread tile 8m x 4n (256 threads). K in 2 chunks of 64.
// LDS: As 16KB + Ws 32KB. Grid: BL/64 = 400.
// ---------------------------------------------------------------------------
__global__ __launch_bounds__(256) void k_gemm(
        const float* __restrict__ A, const float* __restrict__ W,
        const float* __restrict__ bias, const float* __restrict__ res,
        float* __restrict__ out, int relu) {
    __shared__ float As[64 * 64];
    __shared__ float Ws[64 * 128];
    int tid = threadIdx.x;
    int m0 = blockIdx.x * 64;
    int tidn = tid & 31, tidm = tid >> 5;

    float acc[8][4];
#pragma unroll
    for (int j = 0; j < 8; ++j)
#pragma unroll
        for (int n = 0; n < 4; ++n) acc[j][n] = 0.f;

    for (int kc = 0; kc < 128; kc += 64) {
#pragma unroll
        for (int i = 0; i < 4; ++i) {
            int idx = tid + i * 256;
            int r = idx >> 4, c4 = idx & 15;
            *(float4*)(As + r * 64 + c4 * 4) =
                *(const float4*)(A + ((size_t)(m0 + r)) * 128 + kc + c4 * 4);
        }
#pragma unroll
        for (int i = 0; i < 8; ++i) {
            int idx = tid + i * 256;
            int c = idx >> 5, n4 = idx & 31;
            *(float4*)(Ws + c * 128 + n4 * 4) =
                *(const float4*)(W + ((size_t)(kc + c)) * 128 + n4 * 4);
        }
        __syncthreads();
        for (int c4 = 0; c4 < 16; ++c4) {
            float4 a4[8], w4[4];
#pragma unroll
            for (int j = 0; j < 8; ++j)
                a4[j] = *(const float4*)(As + (tidm * 8 + j) * 64 + c4 * 4);
#pragma unroll
            for (int cc = 0; cc < 4; ++cc)
                w4[cc] = *(const float4*)(Ws + (c4 * 4 + cc) * 128 + tidn * 4);
#pragma unroll
            for (int cc = 0; cc < 4; ++cc) {
#pragma unroll
                for (int j = 0; j < 8; ++j) {
                    const float* ap = (const float*)&a4[j];
                    acc[j][0] = fmaf(ap[cc], w4[cc].x, acc[j][0]);
                    acc[j][1] = fmaf(ap[cc], w4[cc].y, acc[j][1]);
                    acc[j][2] = fmaf(ap[cc], w4[cc].z, acc[j][2]);
                    acc[j][3] = fmaf(ap[cc], w4[cc].w, acc[j][3]);
                }
            }
        }
        __syncthreads();
    }

    int n0 = tidn * 4;
    float4 b4 = *(const float4*)(bias + n0);
#pragma unroll
    for (int j = 0; j < 8; ++j) {
        size_t m = (size_t)m0 + tidm * 8 + j;
        float4 v;
        v.x = acc[j][0] + b4.x;
        v.y = acc[j][1] + b4.y;
        v.z = acc[j][2] + b4.z;
        v.w = acc[j][3] + b4.w;
        if (relu) {
            v.x = fmaxf(v.x, 0.f); v.y = fmaxf(v.y, 0.f);
            v.z = fmaxf(v.z, 0.f); v.w = fmaxf(v.w, 0.f);
        }
        if (res) {
            float4 r4 = *(const float4*)(res + m * 128 + n0);
            v.x += r4.x; v.y += r4.y; v.z += r4.z; v.w += r4.w;
        }
        *(float4*)(out + m * 128 + n0) = v;
    }
}

// ---------------------------------------------------------------------------
// Kernel 5: attention. One block per (b,h). K,V staged in LDS (51.2 KB).
// Online-softmax flash per q-row; thread handles rows tid, tid+256.
// Grid: B*H = 512, block 256.
// ---------------------------------------------------------------------------
__global__ __launch_bounds__(256) void k_attn(
        const float* __restrict__ q, const float* __restrict__ k,
        const float* __restrict__ v, float* __restrict__ out) {
    __shared__ float Ks[L * HD];
    __shared__ float Vs[L * HD];
    int tid = threadIdx.x;
    int b = blockIdx.x >> 3, h = blockIdx.x & 7;

    for (int idx = tid; idx < L * HD / 4; idx += 256) {
        int l = idx >> 2, j4 = idx & 3;
        size_t g = ((size_t)b * L + l) * D + h * HD + j4 * 4;
        *(float4*)(Ks + l * HD + j4 * 4) = *(const float4*)(k + g);
        *(float4*)(Vs + l * HD + j4 * 4) = *(const float4*)(v + g);
    }
    __syncthreads();

    for (int r = tid; r < L; r += 256) {
        float qr[16];
#pragma unroll
        for (int j4 = 0; j4 < 4; ++j4)
            *(float4*)(qr + j4 * 4) =
                *(const float4*)(q + ((size_t)b * L + r) * D + h * HD + j4 * 4);
        float m = -1e30f, ssum = 0.f;
        float o[16];
#pragma unroll
        for (int j = 0; j < 16; ++j) o[j] = 0.f;

        for (int kk = 0; kk < L; ++kk) {
            float dot = 0.f;
#pragma unroll
            for (int j4 = 0; j4 < 4; ++j4) {
                float4 kv = *(const float4*)(Ks + kk * HD + j4 * 4);
                dot = fmaf(qr[j4 * 4 + 0], kv.x, dot);
                dot = fmaf(qr[j4 * 4 + 1], kv.y, dot);
                dot = fmaf(qr[j4 * 4 + 2], kv.z, dot);
                dot = fmaf(qr[j4 * 4 + 3], kv.w, dot);
            }
            float sc = dot * 0.25f;  // 1/sqrt(16)
            float nm = fmaxf(m, sc);
            float corr = __expf(m - nm);
            float p = __expf(sc - nm);
            ssum = ssum * corr + p;
#pragma unroll
            for (int j4 = 0; j4 < 4; ++j4) {
                float4 vv = *(const float4*)(Vs + kk * HD + j4 * 4);
                o[j4 * 4 + 0] = fmaf(p, vv.x, o[j4 * 4 + 0] * corr);
                o[j4 * 4 + 1] = fmaf(p, vv.y, o[j4 * 4 + 1] * corr);
                o[j4 * 4 + 2] = fmaf(p, vv.z, o[j4 * 4 + 2] * corr);
                o[j4 * 4 + 3] = fmaf(p, vv.w, o[j4 * 4 + 3] * corr);
            }
            m = nm;
        }
        float inv = 1.f / ssum;
#pragma unroll
        for (int j4 = 0; j4 < 4; ++j4) {
            float4 ov;
            ov.x = o[j4 * 4 + 0] * inv;
            ov.y = o[j4 * 4 + 1] * inv;
            ov.z = o[j4 * 4 + 2] * inv;
            ov.w = o[j4 * 4 + 3] * inv;
            *(float4*)(out + ((size_t)b * L + r) * D + h * HD + j4 * 4) = ov;
        }
    }
}

// ---------------------------------------------------------------------------
extern "C" void kernel_launch(void* const* d_in, const int* in_sizes, int n_in,
                              void* d_out, int out_size, void* d_ws, size_t ws_size,
                              hipStream_t stream) {
    (void)in_sizes; (void)n_in; (void)out_size; (void)ws_size;
    const float* x      = (const float*)d_in[0];
    const float* w_init = (const float*)d_in[1];
    const float* b_init = (const float*)d_in[2];
    const float* lncg   = (const float*)d_in[3];
    const float* lncb   = (const float*)d_in[4];
    const float* w_dw   = (const float*)d_in[5];
    const float* b_dw   = (const float*)d_in[6];
    const float* w_pw   = (const float*)d_in[7];
    const float* b_pw   = (const float*)d_in[8];
    const float* lnag   = (const float*)d_in[9];
    const float* lnab   = (const float*)d_in[10];
    const float* wq     = (const float*)d_in[11];
    const float* bq     = (const float*)d_in[12];
    const float* wk     = (const float*)d_in[13];
    const float* bk     = (const float*)d_in[14];
    const float* wv     = (const float*)d_in[15];
    const float* bv     = (const float*)d_in[16];
    const float* wo     = (const float*)d_in[17];
    const float* bo     = (const float*)d_in[18];
    const float* lnfg   = (const float*)d_in[19];
    const float* lnfb   = (const float*)d_in[20];
    const float* w1     = (const float*)d_in[21];
    const float* b1     = (const float*)d_in[22];
    const float* w2     = (const float*)d_in[23];
    const float* b2     = (const float*)d_in[24];

    float* ws = (float*)d_ws;
    const size_t NBL = (size_t)BL * D;   // 3,276,800 floats
    float* h0 = ws;
    float* hn = ws + NBL;
    float* t0 = ws + 2 * NBL;
    float* qb = ws + 3 * NBL;
    float* kb = ws + 4 * NBL;
    float* vb = ws + 5 * NBL;
    float* outp = (float*)d_out;

    // 1) init conv + posenc
    k_initconv<<<1600, 128, 0, stream>>>(x, w_init, b_init, h0);

    // 2) 4x depthwise-separable conv blocks (pre-LN, residual)
    for (int i = 0; i < NCONV; ++i) {
        k_ln<<<6400, 256, 0, stream>>>(h0, lncg + i * D, lncb + i * D, hn);
        k_dw<<<1600, 256, 0, stream>>>(hn, w_dw + (size_t)i * 7 * D, b_dw + i * D, t0);
        k_gemm<<<400, 256, 0, stream>>>(t0, w_pw + (size_t)i * D * D, b_pw + i * D,
                                        h0, h0, 1);
    }

    // 3) attention
    k_ln<<<6400, 256, 0, stream>>>(h0, lnag, lnab, hn);
    k_gemm<<<400, 256, 0, stream>>>(hn, wq, bq, nullptr, qb, 0);
    k_gemm<<<400, 256, 0, stream>>>(hn, wk, bk, nullptr, kb, 0);
    k_gemm<<<400, 256, 0, stream>>>(hn, wv, bv, nullptr, vb, 0);
    k_attn<<<512, 256, 0, stream>>>(qb, kb, vb, t0);
    k_gemm<<<400, 256, 0, stream>>>(t0, wo, bo, h0, h0, 0);

    // 4) FFN
    k_ln<<<6400, 256, 0, stream>>>(h0, lnfg, lnfb, hn);
    k_gemm<<<400, 256, 0, stream>>>(hn, w1, b1, nullptr, t0, 1);
    k_gemm<<<400, 256, 0, stream>>>(t0, w2, b2, h0, outp, 0);
}

// Round 2
// 685.497 us; speedup vs baseline: 1.2755x; 1.2755x over previous
//
#include <hip/hip_runtime.h>
#include <hip/hip_bf16.h>
#include <math.h>

#define B 64
#define L 400
#define IN_DIM 500
#define D 128
#define H 8
#define HD 16
#define NCONV 4
#define BL (B*L)

typedef __attribute__((ext_vector_type(8))) unsigned short ushort8;
typedef __attribute__((ext_vector_type(8))) short bf16x8;
typedef __attribute__((ext_vector_type(4))) float f32x4;

__device__ __forceinline__ unsigned short f2bf(float f) {
    unsigned u = __float_as_uint(f);
    unsigned r = (u + 0x7fffu + ((u >> 16) & 1u)) >> 16;
    return (unsigned short)r;
}

__device__ __forceinline__ void gload16(const void* g, void* l) {
    __builtin_amdgcn_global_load_lds(
        (const __attribute__((address_space(1))) unsigned int*)g,
        (__attribute__((address_space(3))) unsigned int*)l,
        16, 0, 0);
}

// ---------------------------------------------------------------------------
// Pre-pass A: x fp32 [B,400,500] -> bf16 [B,404,512]; 2 zero guard rows
// top/bottom per batch, K padded 500->512 with zeros.
// Grid: 64*404*64 chunks / 256 = 6464 blocks.
// ---------------------------------------------------------------------------
__global__ __launch_bounds__(256) void k_cvt_x(
        const float* __restrict__ x, unsigned short* __restrict__ xb) {
    int idx = blockIdx.x * 256 + threadIdx.x;   // chunk of 8 bf16
    int row = idx >> 6, ch = idx & 63;
    int b = row / 404, rr = row - b * 404;
    ushort8 o = (ushort8)0;
    if (rr >= 2 && rr < 402) {
        int l = rr - 2;
        const float* src = x + ((size_t)b * 400 + l) * 500 + ch * 8;
        if (ch < 62) {
            float4 v0 = *(const float4*)(src);
            float4 v1 = *(const float4*)(src + 4);
            o[0] = f2bf(v0.x); o[1] = f2bf(v0.y); o[2] = f2bf(v0.z); o[3] = f2bf(v0.w);
            o[4] = f2bf(v1.x); o[5] = f2bf(v1.y); o[6] = f2bf(v1.z); o[7] = f2bf(v1.w);
        } else {
#pragma unroll
            for (int j = 0; j < 8; ++j) {
                int c = ch * 8 + j;
                o[j] = (c < 500) ? f2bf(src[j]) : (unsigned short)0;
            }
        }
    }
    *(ushort8*)(xb + (size_t)idx * 8) = o;
}

// ---------------------------------------------------------------------------
// Pre-pass B: w fp32 [5,500,128] -> bf16 transposed+padded [5,128,512].
// wbt[t][n][k] = w[t,k,n] (k<500) else 0.  Grid: 327680/256 = 1280.
// ---------------------------------------------------------------------------
__global__ __launch_bounds__(256) void k_cvt_w(
        const float* __restrict__ w, unsigned short* __restrict__ wbt) {
    int idx = blockIdx.x * 256 + threadIdx.x;
    int k = idx & 511, n = (idx >> 9) & 127, t = idx >> 16;
    float v = (k < 500) ? w[((size_t)t * 500 + k) * 128 + n] : 0.f;
    wbt[idx] = f2bf(v);
}

// ---------------------------------------------------------------------------
// Kernel 1: init conv as MFMA implicit GEMM + bias + posenc.
// Block tile 80m x 128n; 4 waves, each 80m x 32n (5x2 frags of 16x16).
// K-loop: 5 taps x 8 chunks of BK=64, global_load_lds(16B), XOR swizzle.
// Grid: 64 b * 5 ltiles = 320, block 256.
// ---------------------------------------------------------------------------
#define TM 80
#define BK 64
__global__ __launch_bounds__(256) void k_initconv_mfma(
        const unsigned short* __restrict__ xb,
        const unsigned short* __restrict__ wbt,
        const float* __restrict__ bias, float* __restrict__ out) {
    __shared__ unsigned short As[TM * BK];     // 10 KB
    __shared__ unsigned short Ws[128 * BK];    // 16 KB
    int tid = threadIdx.x;
    int b = blockIdx.x / 5;
    int l0 = (blockIdx.x - b * 5) * TM;
    int lane = tid & 63, wave = tid >> 6;
    int kgrp = lane >> 4, lm = lane & 15;

    f32x4 acc[5][2];
#pragma unroll
    for (int mf = 0; mf < 5; ++mf)
#pragma unroll
        for (int nf = 0; nf < 2; ++nf) acc[mf][nf] = (f32x4)0.f;

    for (int t = 0; t < 5; ++t) {
        const unsigned short* arow = xb + ((size_t)(b * 404 + l0 + t)) * 512;
        const unsigned short* wrow = wbt + (size_t)t * 128 * 512;
        for (int k0 = 0; k0 < 512; k0 += BK) {
            // stage A: 640 16B chunks, swizzled: slot(r,sc) <- global chunk sc^(r&7)
            {
                int idx = tid;
#pragma unroll
                for (int i = 0; i < 2; ++i) {
                    int r = idx >> 3, sc = idx & 7;
                    gload16(arow + (size_t)r * 512 + k0 + ((sc ^ (r & 7)) * 8),
                            As + idx * 8);
                    idx += 256;
                }
                if (idx < 640) {
                    int r = idx >> 3, sc = idx & 7;
                    gload16(arow + (size_t)r * 512 + k0 + ((sc ^ (r & 7)) * 8),
                            As + idx * 8);
                }
            }
            // stage W: 1024 16B chunks, same swizzle on n
#pragma unroll
            for (int i = 0; i < 4; ++i) {
                int idx = tid + i * 256;
                int n = idx >> 3, sc = idx & 7;
                gload16(wrow + (size_t)n * 512 + k0 + ((sc ^ (n & 7)) * 8),
                        Ws + idx * 8);
            }
            __syncthreads();
#pragma unroll
            for (int ks = 0; ks < 2; ++ks) {
                bf16x8 af[5], bfr[2];
#pragma unroll
                for (int mf = 0; mf < 5; ++mf) {
                    int r = mf * 16 + lm;
                    int gc = ks * 4 + kgrp;
                    af[mf] = *(const bf16x8*)(As + r * 64 + ((gc ^ (r & 7)) * 8));
                }
#pragma unroll
                for (int nf = 0; nf < 2; ++nf) {
                    int n = wave * 32 + nf * 16 + lm;
                    int gc = ks * 4 + kgrp;
                    bfr[nf] = *(const bf16x8*)(Ws + n * 64 + ((gc ^ (n & 7)) * 8));
                }
#pragma unroll
                for (int mf = 0; mf < 5; ++mf)
#pragma unroll
                    for (int nf = 0; nf < 2; ++nf)
                        acc[mf][nf] = __builtin_amdgcn_mfma_f32_16x16x32_bf16(
                            af[mf], bfr[nf], acc[mf][nf], 0, 0, 0);
            }
            __syncthreads();
        }
    }

    // epilogue: + bias + posenc, C/D layout col=lane&15, row=kgrp*4+reg
#pragma unroll
    for (int nf = 0; nf < 2; ++nf) {
        int n = wave * 32 + nf * 16 + lm;
        float bs = bias[n];
        float pbase = expf(-(float)(n & ~1) * (9.210340371976184f / 128.0f));
#pragma unroll
        for (int mf = 0; mf < 5; ++mf) {
#pragma unroll
            for (int r = 0; r < 4; ++r) {
                int l = l0 + mf * 16 + kgrp * 4 + r;
                float ang = (float)l * pbase;
                float pe = (n & 1) ? cosf(ang) : sinf(ang);
                out[((size_t)b * 400 + l) * 128 + n] = acc[mf][nf][r] + bs + pe;
            }
        }
    }
}

// ---------------------------------------------------------------------------
// Kernel 2: LayerNorm over last dim (128). One wave per row, 4 rows/block.
// ---------------------------------------------------------------------------
__global__ __launch_bounds__(256) void k_ln(
        const float* __restrict__ in, const float* __restrict__ g,
        const float* __restrict__ bta, float* __restrict__ out) {
    int wave = threadIdx.x >> 6, lane = threadIdx.x & 63;
    size_t row = (size_t)blockIdx.x * 4 + wave;
    const float* p = in + row * D;
    float2 v = *(const float2*)(p + lane * 2);
    float s = v.x + v.y;
    float q = v.x * v.x + v.y * v.y;
#pragma unroll
    for (int off = 32; off; off >>= 1) {
        s += __shfl_xor(s, off);
        q += __shfl_xor(q, off);
    }
    float mu  = s * (1.f / 128.f);
    float var = q * (1.f / 128.f) - mu * mu;
    float inv = rsqrtf(var + 1e-5f);
    float2 gg = *(const float2*)(g + lane * 2);
    float2 bb = *(const float2*)(bta + lane * 2);
    float2 o;
    o.x = (v.x - mu) * inv * gg.x + bb.x;
    o.y = (v.y - mu) * inv * gg.y + bb.y;
    *(float2*)(out + row * D + lane * 2) = o;
}

// ---------------------------------------------------------------------------
// Kernel 3: depthwise conv k=7 pad=3 + bias.
// ---------------------------------------------------------------------------
__global__ __launch_bounds__(256) void k_dw(
        const float* __restrict__ in, const float* __restrict__ w,
        const float* __restrict__ bias, float* __restrict__ out) {
    __shared__ float s[22 * D];
    int tid = threadIdx.x;
    int b  = blockIdx.x / 25;
    int l0 = (blockIdx.x - b * 25) * 16;
    for (int idx = tid; idx < 22 * D; idx += 256) {
        int r = idx >> 7, d = idx & 127;
        int gl = l0 - 3 + r;
        s[idx] = (gl >= 0 && gl < L) ? in[((size_t)b * L + gl) * D + d] : 0.f;
    }
    __syncthreads();
    int d = tid & 127, half = tid >> 7;
    float wr[7];
#pragma unroll
    for (int t = 0; t < 7; ++t) wr[t] = w[t * D + d];
    float bs = bias[d];
    for (int jj = 0; jj < 8; ++jj) {
        int lj = half * 8 + jj;
        float a = bs;
#pragma unroll
        for (int t = 0; t < 7; ++t) a = fmaf(s[(lj + t) * D + d], wr[t], a);
        out[((size_t)b * L + l0 + lj) * D + d] = a;
    }
}

// ---------------------------------------------------------------------------
// Kernel 4: generic [BL,128] x [128,128] fp32 GEMM, fused bias/relu/residual.
// ---------------------------------------------------------------------------
__global__ __launch_bounds__(256) void k_gemm(
        const float* __restrict__ A, const float* __restrict__ W,
        const float* __restrict__ bias, const float* __restrict__ res,
        float* __restrict__ out, int relu) {
    __shared__ float As[64 * 64];
    __shared__ float Ws[64 * 128];
    int tid = threadIdx.x;
    int m0 = blockIdx.x * 64;
    int tidn = tid & 31, tidm = tid >> 5;

    float acc[8][4];
#pragma unroll
    for (int j = 0; j < 8; ++j)
#pragma unroll
        for (int n = 0; n < 4; ++n) acc[j][n] = 0.f;

    for (int kc = 0; kc < 128; kc += 64) {
#pragma unroll
        for (int i = 0; i < 4; ++i) {
            int idx = tid + i * 256;
            int r = idx >> 4, c4 = idx & 15;
            *(float4*)(As + r * 64 + c4 * 4) =
                *(const float4*)(A + ((size_t)(m0 + r)) * 128 + kc + c4 * 4);
        }
#pragma unroll
        for (int i = 0; i < 8; ++i) {
            int idx = tid + i * 256;
            int c = idx >> 5, n4 = idx & 31;
            *(float4*)(Ws + c * 128 + n4 * 4) =
                *(const float4*)(W + ((size_t)(kc + c)) * 128 + n4 * 4);
        }
        __syncthreads();
        for (int c4 = 0; c4 < 16; ++c4) {
            float4 a4[8], w4[4];
#pragma unroll
            for (int j = 0; j < 8; ++j)
                a4[j] = *(const float4*)(As + (tidm * 8 + j) * 64 + c4 * 4);
#pragma unroll
            for (int cc = 0; cc < 4; ++cc)
                w4[cc] = *(const float4*)(Ws + (c4 * 4 + cc) * 128 + tidn * 4);
#pragma unroll
            for (int cc = 0; cc < 4; ++cc) {
#pragma unroll
                for (int j = 0; j < 8; ++j) {
                    const float* ap = (const float*)&a4[j];
                    acc[j][0] = fmaf(ap[cc], w4[cc].x, acc[j][0]);
                    acc[j][1] = fmaf(ap[cc], w4[cc].y, acc[j][1]);
                    acc[j][2] = fmaf(ap[cc], w4[cc].z, acc[j][2]);
                    acc[j][3] = fmaf(ap[cc], w4[cc].w, acc[j][3]);
                }
            }
        }
        __syncthreads();
    }

    int n0 = tidn * 4;
    float4 b4 = *(const float4*)(bias + n0);
#pragma unroll
    for (int j = 0; j < 8; ++j) {
        size_t m = (size_t)m0 + tidm * 8 + j;
        float4 v;
        v.x = acc[j][0] + b4.x;
        v.y = acc[j][1] + b4.y;
        v.z = acc[j][2] + b4.z;
        v.w = acc[j][3] + b4.w;
        if (relu) {
            v.x = fmaxf(v.x, 0.f); v.y = fmaxf(v.y, 0.f);
            v.z = fmaxf(v.z, 0.f); v.w = fmaxf(v.w, 0.f);
        }
        if (res) {
            float4 r4 = *(const float4*)(res + m * 128 + n0);
            v.x += r4.x; v.y += r4.y; v.z += r4.z; v.w += r4.w;
        }
        *(float4*)(out + m * 128 + n0) = v;
    }
}

// ---------------------------------------------------------------------------
// Kernel 5: attention. One block per (b,h). K,V staged in LDS.
// ---------------------------------------------------------------------------
__global__ __launch_bounds__(256) void k_attn(
        const float* __restrict__ q, const float* __restrict__ k,
        const float* __restrict__ v, float* __restrict__ out) {
    __shared__ float Ks[L * HD];
    __shared__ float Vs[L * HD];
    int tid = threadIdx.x;
    int b = blockIdx.x >> 3, h = blockIdx.x & 7;

    for (int idx = tid; idx < L * HD / 4; idx += 256) {
        int l = idx >> 2, j4 = idx & 3;
        size_t g = ((size_t)b * L + l) * D + h * HD + j4 * 4;
        *(float4*)(Ks + l * HD + j4 * 4) = *(const float4*)(k + g);
        *(float4*)(Vs + l * HD + j4 * 4) = *(const float4*)(v + g);
    }
    __syncthreads();

    for (int r = tid; r < L; r += 256) {
        float qr[16];
#pragma unroll
        for (int j4 = 0; j4 < 4; ++j4)
            *(float4*)(qr + j4 * 4) =
                *(const float4*)(q + ((size_t)b * L + r) * D + h * HD + j4 * 4);
        float m = -1e30f, ssum = 0.f;
        float o[16];
#pragma unroll
        for (int j = 0; j < 16; ++j) o[j] = 0.f;

        for (int kk = 0; kk < L; ++kk) {
            float dot = 0.f;
#pragma unroll
            for (int j4 = 0; j4 < 4; ++j4) {
                float4 kv = *(const float4*)(Ks + kk * HD + j4 * 4);
                dot = fmaf(qr[j4 * 4 + 0], kv.x, dot);
                dot = fmaf(qr[j4 * 4 + 1], kv.y, dot);
                dot = fmaf(qr[j4 * 4 + 2], kv.z, dot);
                dot = fmaf(qr[j4 * 4 + 3], kv.w, dot);
            }
            float sc = dot * 0.25f;
            float nm = fmaxf(m, sc);
            float corr = __expf(m - nm);
            float p = __expf(sc - nm);
            ssum = ssum * corr + p;
#pragma unroll
            for (int j4 = 0; j4 < 4; ++j4) {
                float4 vv = *(const float4*)(Vs + kk * HD + j4 * 4);
                o[j4 * 4 + 0] = fmaf(p, vv.x, o[j4 * 4 + 0] * corr);
                o[j4 * 4 + 1] = fmaf(p, vv.y, o[j4 * 4 + 1] * corr);
                o[j4 * 4 + 2] = fmaf(p, vv.z, o[j4 * 4 + 2] * corr);
                o[j4 * 4 + 3] = fmaf(p, vv.w, o[j4 * 4 + 3] * corr);
            }
            m = nm;
        }
        float inv = 1.f / ssum;
#pragma unroll
        for (int j4 = 0; j4 < 4; ++j4) {
            float4 ov;
            ov.x = o[j4 * 4 + 0] * inv;
            ov.y = o[j4 * 4 + 1] * inv;
            ov.z = o[j4 * 4 + 2] * inv;
            ov.w = o[j4 * 4 + 3] * inv;
            *(float4*)(out + ((size_t)b * L + r) * D + h * HD + j4 * 4) = ov;
        }
    }
}

// ---------------------------------------------------------------------------
extern "C" void kernel_launch(void* const* d_in, const int* in_sizes, int n_in,
                              void* d_out, int out_size, void* d_ws, size_t ws_size,
                              hipStream_t stream) {
    (void)in_sizes; (void)n_in; (void)out_size; (void)ws_size;
    const float* x      = (const float*)d_in[0];
    const float* w_init = (const float*)d_in[1];
    const float* b_init = (const float*)d_in[2];
    const float* lncg   = (const float*)d_in[3];
    const float* lncb   = (const float*)d_in[4];
    const float* w_dw   = (const float*)d_in[5];
    const float* b_dw   = (const float*)d_in[6];
    const float* w_pw   = (const float*)d_in[7];
    const float* b_pw   = (const float*)d_in[8];
    const float* lnag   = (const float*)d_in[9];
    const float* lnab   = (const float*)d_in[10];
    const float* wq     = (const float*)d_in[11];
    const float* bq     = (const float*)d_in[12];
    const float* wk     = (const float*)d_in[13];
    const float* bk     = (const float*)d_in[14];
    const float* wv     = (const float*)d_in[15];
    const float* bv     = (const float*)d_in[16];
    const float* wo     = (const float*)d_in[17];
    const float* bo     = (const float*)d_in[18];
    const float* lnfg   = (const float*)d_in[19];
    const float* lnfb   = (const float*)d_in[20];
    const float* w1     = (const float*)d_in[21];
    const float* b1     = (const float*)d_in[22];
    const float* w2     = (const float*)d_in[23];
    const float* b2     = (const float*)d_in[24];

    float* ws = (float*)d_ws;
    const size_t NBL = (size_t)BL * D;   // 3,276,800 floats
    float* h0 = ws;
    float* hn = ws + NBL;
    float* t0 = ws + 2 * NBL;
    float* qb = ws + 3 * NBL;
    float* kb = ws + 4 * NBL;
    float* vb = ws + 5 * NBL;
    float* outp = (float*)d_out;

    // phase-1 scratch overlaps qb/kb/vb (not live yet):
    unsigned short* xb  = (unsigned short*)(ws + 3 * NBL);   // 64*404*512 bf16
    unsigned short* wbt = xb + (size_t)64 * 404 * 512;       // 5*128*512 bf16

    // 1) init conv + posenc (bf16 MFMA implicit GEMM)
    k_cvt_x<<<6464, 256, 0, stream>>>(x, xb);
    k_cvt_w<<<1280, 256, 0, stream>>>(w_init, wbt);
    k_initconv_mfma<<<320, 256, 0, stream>>>(xb, wbt, b_init, h0);

    // 2) 4x depthwise-separable conv blocks (pre-LN, residual)
    for (int i = 0; i < NCONV; ++i) {
        k_ln<<<6400, 256, 0, stream>>>(h0, lncg + i * D, lncb + i * D, hn);
        k_dw<<<1600, 256, 0, stream>>>(hn, w_dw + (size_t)i * 7 * D, b_dw + i * D, t0);
        k_gemm<<<400, 256, 0, stream>>>(t0, w_pw + (size_t)i * D * D, b_pw + i * D,
                                        h0, h0, 1);
    }

    // 3) attention
    k_ln<<<6400, 256, 0, stream>>>(h0, lnag, lnab, hn);
    k_gemm<<<400, 256, 0, stream>>>(hn, wq, bq, nullptr, qb, 0);
    k_gemm<<<400, 256, 0, stream>>>(hn, wk, bk, nullptr, kb, 0);
    k_gemm<<<400, 256, 0, stream>>>(hn, wv, bv, nullptr, vb, 0);
    k_attn<<<512, 256, 0, stream>>>(qb, kb, vb, t0);
    k_gemm<<<400, 256, 0, stream>>>(t0, wo, bo, h0, h0, 0);

    // 4) FFN
    k_ln<<<6400, 256, 0, stream>>>(h0, lnfg, lnfb, hn);
    k_gemm<<<400, 256, 0, stream>>>(hn, w1, b1, nullptr, t0, 1);
    k_gemm<<<400, 256, 0, stream>>>(t0, w2, b2, h0, outp, 0);
}

// Round 3
// 504.928 us; speedup vs baseline: 1.7316x; 1.3576x over previous
//
#include <hip/hip_runtime.h>
#include <hip/hip_bf16.h>
#include <math.h>

#define B 64
#define L 400
#define IN_DIM 500
#define D 128
#define H 8
#define HD 16
#define NCONV 4
#define BL (B*L)

typedef __attribute__((ext_vector_type(8))) unsigned short ushort8;
typedef __attribute__((ext_vector_type(8))) short bf16x8;
typedef __attribute__((ext_vector_type(4))) float f32x4;

__device__ __forceinline__ unsigned short f2bf(float f) {
    unsigned u = __float_as_uint(f);
    unsigned r = (u + 0x7fffu + ((u >> 16) & 1u)) >> 16;
    return (unsigned short)r;
}
__device__ __forceinline__ float bf2f(unsigned short u) {
    return __uint_as_float(((unsigned)u) << 16);
}

__device__ __forceinline__ void gload16(const void* g, void* l) {
    __builtin_amdgcn_global_load_lds(
        (const __attribute__((address_space(1))) unsigned int*)g,
        (__attribute__((address_space(3))) unsigned int*)l,
        16, 0, 0);
}

// ---------------------------------------------------------------------------
// Pre-pass A: x fp32 [B,400,500] -> bf16 [B,404,512]; 2 zero guard rows.
// ---------------------------------------------------------------------------
__global__ __launch_bounds__(256) void k_cvt_x(
        const float* __restrict__ x, unsigned short* __restrict__ xb) {
    int idx = blockIdx.x * 256 + threadIdx.x;   // chunk of 8 bf16
    int row = idx >> 6, ch = idx & 63;
    int b = row / 404, rr = row - b * 404;
    ushort8 o = (ushort8)0;
    if (rr >= 2 && rr < 402) {
        int l = rr - 2;
        const float* src = x + ((size_t)b * 400 + l) * 500 + ch * 8;
        if (ch < 62) {
            float4 v0 = *(const float4*)(src);
            float4 v1 = *(const float4*)(src + 4);
            o[0] = f2bf(v0.x); o[1] = f2bf(v0.y); o[2] = f2bf(v0.z); o[3] = f2bf(v0.w);
            o[4] = f2bf(v1.x); o[5] = f2bf(v1.y); o[6] = f2bf(v1.z); o[7] = f2bf(v1.w);
        } else {
#pragma unroll
            for (int j = 0; j < 8; ++j) {
                int c = ch * 8 + j;
                o[j] = (c < 500) ? f2bf(src[j]) : (unsigned short)0;
            }
        }
    }
    *(ushort8*)(xb + (size_t)idx * 8) = o;
}

// ---------------------------------------------------------------------------
// Pre-pass B: w_init fp32 [5,500,128] -> bf16 transposed+padded [5,128,512].
// ---------------------------------------------------------------------------
__global__ __launch_bounds__(256) void k_cvt_w(
        const float* __restrict__ w, unsigned short* __restrict__ wbt) {
    int idx = blockIdx.x * 256 + threadIdx.x;
    int k = idx & 511, n = (idx >> 9) & 127, t = idx >> 16;
    float v = (k < 500) ? w[((size_t)t * 500 + k) * 128 + n] : 0.f;
    wbt[idx] = f2bf(v);
}

// ---------------------------------------------------------------------------
// Pre-pass C: 10 [128,128] fp32 weights -> bf16 transposed wt[n][k].
// Order: pw0..pw3, wq, wk, wv, wo, w1, w2.  Grid 640.
// ---------------------------------------------------------------------------
__global__ __launch_bounds__(256) void k_cvt_wall(
        const float* w0, const float* w1, const float* w2, const float* w3,
        const float* w4, const float* w5, const float* w6, const float* w7,
        const float* w8, const float* w9, unsigned short* __restrict__ out) {
    const float* arr[10] = {w0,w1,w2,w3,w4,w5,w6,w7,w8,w9};
    int widx = blockIdx.x >> 6;
    const float* w = arr[widx];
    int idx = ((blockIdx.x & 63) << 8) + threadIdx.x;  // 0..16383 = n*128+k
    int n = idx >> 7, k = idx & 127;
    out[(size_t)widx * 16384 + idx] = f2bf(w[k * 128 + n]);
}

// ---------------------------------------------------------------------------
// Kernel 1: init conv as MFMA implicit GEMM + bias + posenc. (unchanged R2)
// ---------------------------------------------------------------------------
#define TM 80
#define BK 64
__global__ __launch_bounds__(256) void k_initconv_mfma(
        const unsigned short* __restrict__ xb,
        const unsigned short* __restrict__ wbt,
        const float* __restrict__ bias, float* __restrict__ out) {
    __shared__ unsigned short As[TM * BK];
    __shared__ unsigned short Ws[128 * BK];
    int tid = threadIdx.x;
    int b = blockIdx.x / 5;
    int l0 = (blockIdx.x - b * 5) * TM;
    int lane = tid & 63, wave = tid >> 6;
    int kgrp = lane >> 4, lm = lane & 15;

    f32x4 acc[5][2];
#pragma unroll
    for (int mf = 0; mf < 5; ++mf)
#pragma unroll
        for (int nf = 0; nf < 2; ++nf) acc[mf][nf] = (f32x4)0.f;

    for (int t = 0; t < 5; ++t) {
        const unsigned short* arow = xb + ((size_t)(b * 404 + l0 + t)) * 512;
        const unsigned short* wrow = wbt + (size_t)t * 128 * 512;
        for (int k0 = 0; k0 < 512; k0 += BK) {
            {
                int idx = tid;
#pragma unroll
                for (int i = 0; i < 2; ++i) {
                    int r = idx >> 3, sc = idx & 7;
                    gload16(arow + (size_t)r * 512 + k0 + ((sc ^ (r & 7)) * 8),
                            As + idx * 8);
                    idx += 256;
                }
                if (idx < 640) {
                    int r = idx >> 3, sc = idx & 7;
                    gload16(arow + (size_t)r * 512 + k0 + ((sc ^ (r & 7)) * 8),
                            As + idx * 8);
                }
            }
#pragma unroll
            for (int i = 0; i < 4; ++i) {
                int idx = tid + i * 256;
                int n = idx >> 3, sc = idx & 7;
                gload16(wrow + (size_t)n * 512 + k0 + ((sc ^ (n & 7)) * 8),
                        Ws + idx * 8);
            }
            __syncthreads();
#pragma unroll
            for (int ks = 0; ks < 2; ++ks) {
                bf16x8 af[5], bfr[2];
#pragma unroll
                for (int mf = 0; mf < 5; ++mf) {
                    int r = mf * 16 + lm;
                    int gc = ks * 4 + kgrp;
                    af[mf] = *(const bf16x8*)(As + r * 64 + ((gc ^ (r & 7)) * 8));
                }
#pragma unroll
                for (int nf = 0; nf < 2; ++nf) {
                    int n = wave * 32 + nf * 16 + lm;
                    int gc = ks * 4 + kgrp;
                    bfr[nf] = *(const bf16x8*)(Ws + n * 64 + ((gc ^ (n & 7)) * 8));
                }
#pragma unroll
                for (int mf = 0; mf < 5; ++mf)
#pragma unroll
                    for (int nf = 0; nf < 2; ++nf)
                        acc[mf][nf] = __builtin_amdgcn_mfma_f32_16x16x32_bf16(
                            af[mf], bfr[nf], acc[mf][nf], 0, 0, 0);
            }
            __syncthreads();
        }
    }

#pragma unroll
    for (int nf = 0; nf < 2; ++nf) {
        int n = wave * 32 + nf * 16 + lm;
        float bs = bias[n];
        float pbase = expf(-(float)(n & ~1) * (9.210340371976184f / 128.0f));
#pragma unroll
        for (int mf = 0; mf < 5; ++mf) {
#pragma unroll
            for (int r = 0; r < 4; ++r) {
                int l = l0 + mf * 16 + kgrp * 4 + r;
                float ang = (float)l * pbase;
                float pe = (n & 1) ? cosf(ang) : sinf(ang);
                out[((size_t)b * 400 + l) * 128 + n] = acc[mf][nf][r] + bs + pe;
            }
        }
    }
}

// ---------------------------------------------------------------------------
// Kernel 2: LayerNorm fp32 in -> bf16 out. One wave/row, 4 rows/block.
// ---------------------------------------------------------------------------
__global__ __launch_bounds__(256) void k_ln(
        const float* __restrict__ in, const float* __restrict__ g,
        const float* __restrict__ bta, unsigned short* __restrict__ out) {
    int wave = threadIdx.x >> 6, lane = threadIdx.x & 63;
    size_t row = (size_t)blockIdx.x * 4 + wave;
    const float* p = in + row * D;
    float2 v = *(const float2*)(p + lane * 2);
    float s = v.x + v.y;
    float q = v.x * v.x + v.y * v.y;
#pragma unroll
    for (int off = 32; off; off >>= 1) {
        s += __shfl_xor(s, off);
        q += __shfl_xor(q, off);
    }
    float mu  = s * (1.f / 128.f);
    float var = q * (1.f / 128.f) - mu * mu;
    float inv = rsqrtf(var + 1e-5f);
    float2 gg = *(const float2*)(g + lane * 2);
    float2 bb = *(const float2*)(bta + lane * 2);
    float ox = (v.x - mu) * inv * gg.x + bb.x;
    float oy = (v.y - mu) * inv * gg.y + bb.y;
    unsigned pk = (unsigned)f2bf(ox) | ((unsigned)f2bf(oy) << 16);
    *(unsigned*)(out + row * D + lane * 2) = pk;
}

// ---------------------------------------------------------------------------
// Kernel 3: depthwise conv k=7 pad=3 + bias, bf16 in/out, fp32 math/weights.
// ---------------------------------------------------------------------------
__global__ __launch_bounds__(256) void k_dw(
        const unsigned short* __restrict__ in, const float* __restrict__ w,
        const float* __restrict__ bias, unsigned short* __restrict__ out) {
    __shared__ float s[22 * D];
    int tid = threadIdx.x;
    int b  = blockIdx.x / 25;
    int l0 = (blockIdx.x - b * 25) * 16;
    for (int idx = tid; idx < 22 * 16; idx += 256) {  // 16 chunks of 8 per row
        int r = idx >> 4, c = idx & 15;
        int gl = l0 - 3 + r;
        float vals[8];
        if (gl >= 0 && gl < L) {
            ushort8 u = *(const ushort8*)(in + ((size_t)b * L + gl) * D + c * 8);
#pragma unroll
            for (int j = 0; j < 8; ++j) vals[j] = bf2f(u[j]);
        } else {
#pragma unroll
            for (int j = 0; j < 8; ++j) vals[j] = 0.f;
        }
#pragma unroll
        for (int j = 0; j < 8; ++j) s[r * D + c * 8 + j] = vals[j];
    }
    __syncthreads();
    int d = tid & 127, half = tid >> 7;
    float wr[7];
#pragma unroll
    for (int t = 0; t < 7; ++t) wr[t] = w[t * D + d];
    float bs = bias[d];
    for (int jj = 0; jj < 8; ++jj) {
        int lj = half * 8 + jj;
        float a = bs;
#pragma unroll
        for (int t = 0; t < 7; ++t) a = fmaf(s[(lj + t) * D + d], wr[t], a);
        out[((size_t)b * L + l0 + lj) * D + d] = f2bf(a);
    }
}

// ---------------------------------------------------------------------------
// Kernel 4: bf16 MFMA GEMM [BL,128] x Wt[128n][128k] with fused epilogue.
// Tile 64m x 128n, grid 400, 4 waves; wave owns 16m x 128n.
// ---------------------------------------------------------------------------
__global__ __launch_bounds__(256) void k_gemm_bf16(
        const unsigned short* __restrict__ A,
        const unsigned short* __restrict__ Wt,
        const float* __restrict__ bias,
        const float* __restrict__ res,
        float* __restrict__ outf,
        unsigned short* __restrict__ outb,
        int relu, float oscale) {
    __shared__ unsigned short As[64 * 128];   // 16 KB, XOR-16 swizzled chunks
    __shared__ unsigned short Ws[128 * 128];  // 32 KB
    int tid = threadIdx.x;
    int m0 = blockIdx.x * 64;
    int lane = tid & 63, wave = tid >> 6;
    int lm = lane & 15, kgrp = lane >> 4;

#pragma unroll
    for (int i = 0; i < 4; ++i) {
        int idx = tid + i * 256;
        int r = idx >> 4, sc = idx & 15;
        gload16(A + ((size_t)(m0 + r)) * 128 + ((sc ^ (r & 15)) * 8), As + idx * 8);
    }
#pragma unroll
    for (int i = 0; i < 8; ++i) {
        int idx = tid + i * 256;
        int n = idx >> 4, sc = idx & 15;
        gload16(Wt + ((size_t)n) * 128 + ((sc ^ (n & 15)) * 8), Ws + idx * 8);
    }
    __syncthreads();

    f32x4 acc[8];
#pragma unroll
    for (int nt = 0; nt < 8; ++nt) acc[nt] = (f32x4)0.f;

#pragma unroll
    for (int kc = 0; kc < 4; ++kc) {
        int c = kc * 4 + kgrp;
        int r = wave * 16 + lm;
        bf16x8 af = *(const bf16x8*)(As + (r * 16 + (c ^ (r & 15))) * 8);
#pragma unroll
        for (int nt = 0; nt < 8; ++nt) {
            int n = nt * 16 + lm;
            bf16x8 bfv = *(const bf16x8*)(Ws + (n * 16 + (c ^ (n & 15))) * 8);
            acc[nt] = __builtin_amdgcn_mfma_f32_16x16x32_bf16(af, bfv, acc[nt], 0, 0, 0);
        }
    }

#pragma unroll
    for (int nt = 0; nt < 8; ++nt) {
        int n = nt * 16 + lm;
        float bs = bias[n];
#pragma unroll
        for (int r = 0; r < 4; ++r) {
            size_t m = (size_t)m0 + wave * 16 + kgrp * 4 + r;
            float v = acc[nt][r] + bs;
            if (relu) v = fmaxf(v, 0.f);
            if (res)  v += res[m * 128 + n];
            if (outf) outf[m * 128 + n] = v;
            else      outb[m * 128 + n] = f2bf(v * oscale);
        }
    }
}

// ---------------------------------------------------------------------------
// Kernel 5: MFMA attention. One block per (b,h), 4 waves, each wave does
// q-tiles of 16 rows round-robin. K padded to k=32 (zeros), V transposed.
// S via 25x mfma_16x16x32; softmax in-register; P->LDS->PV 13x mfma.
// q is pre-scaled by 1/sqrt(HD) in the q-GEMM epilogue. Output bf16.
// ---------------------------------------------------------------------------
#define KS 40    // Kpad row stride (ushorts)
#define VS 424   // Vt row stride (ushorts)
__global__ __launch_bounds__(256) void k_attn_mfma(
        const unsigned short* __restrict__ qb,
        const unsigned short* __restrict__ kb,
        const unsigned short* __restrict__ vb,
        unsigned short* __restrict__ out) {
    __shared__ __align__(16) unsigned short Kpad[400 * KS];  // 32000 B
    __shared__ __align__(16) unsigned short Vt[16 * VS];     // 13568 B
    __shared__ __align__(16) unsigned short Ptmp[4][16 * KS];// 5120 B
    int tid = threadIdx.x;
    int b = blockIdx.x >> 3, h = blockIdx.x & 7;
    int lane = tid & 63, wave = tid >> 6;
    int lm = lane & 15, kgrp = lane >> 4;

    // stage K (valid d 0..15, zeros 16..31)
    for (int idx = tid; idx < 800; idx += 256) {
        int l = idx >> 1, half = idx & 1;
        ushort8 kv = *(const ushort8*)(kb + ((size_t)(b * 400 + l)) * 128 + h * 16 + half * 8);
        *(ushort8*)(Kpad + l * KS + half * 8) = kv;
        *(ushort8*)(Kpad + l * KS + 16 + half * 8) = (ushort8)0;
    }
    // stage V^T: Vt[d][kk]
    for (int idx = tid; idx < 800; idx += 256) {
        int kk = idx >> 1, dh = idx & 1;
        ushort8 vv = *(const ushort8*)(vb + ((size_t)(b * 400 + kk)) * 128 + h * 16 + dh * 8);
#pragma unroll
        for (int j = 0; j < 8; ++j) Vt[(dh * 8 + j) * VS + kk] = vv[j];
    }
    {   // zero kk 400..415
        int d = tid >> 4, kk = 400 + (tid & 15);
        Vt[d * VS + kk] = 0;
    }
    __syncthreads();

    unsigned short* Pw = Ptmp[wave];
    for (int tt = wave; tt < 25; tt += 4) {
        int q0 = tt * 16;
        bf16x8 Qf = *(const bf16x8*)(qb + ((size_t)(b * 400 + q0 + lm)) * 128 + h * 16 + kgrp * 8);
        f32x4 s[25];
#pragma unroll
        for (int kt = 0; kt < 25; ++kt) {
            bf16x8 Kf = *(const bf16x8*)(Kpad + (kt * 16 + lm) * KS + kgrp * 8);
            s[kt] = __builtin_amdgcn_mfma_f32_16x16x32_bf16(Qf, Kf, (f32x4)0.f, 0, 0, 0);
        }
        // softmax over kk: lane holds q rows {kgrp*4+r}, col kk = kt*16+lm
        float rmax[4], rsum[4];
#pragma unroll
        for (int r = 0; r < 4; ++r) rmax[r] = -1e30f;
#pragma unroll
        for (int kt = 0; kt < 25; ++kt)
#pragma unroll
            for (int r = 0; r < 4; ++r) rmax[r] = fmaxf(rmax[r], s[kt][r]);
#pragma unroll
        for (int mask = 1; mask <= 8; mask <<= 1)
#pragma unroll
            for (int r = 0; r < 4; ++r) rmax[r] = fmaxf(rmax[r], __shfl_xor(rmax[r], mask));
#pragma unroll
        for (int r = 0; r < 4; ++r) rsum[r] = 0.f;
#pragma unroll
        for (int kt = 0; kt < 25; ++kt)
#pragma unroll
            for (int r = 0; r < 4; ++r) {
                float p = __expf(s[kt][r] - rmax[r]);
                s[kt][r] = p;
                rsum[r] += p;
            }
#pragma unroll
        for (int mask = 1; mask <= 8; mask <<= 1)
#pragma unroll
            for (int r = 0; r < 4; ++r) rsum[r] += __shfl_xor(rsum[r], mask);
        float rinv[4];
#pragma unroll
        for (int r = 0; r < 4; ++r) rinv[r] = 1.f / rsum[r];

        // PV: 13 chunks of 32 kk
        f32x4 O = (f32x4)0.f;
#pragma unroll
        for (int kc = 0; kc < 13; ++kc) {
#pragma unroll
            for (int t = 0; t < 2; ++t) {
                int kt = kc * 2 + t;
#pragma unroll
                for (int r = 0; r < 4; ++r) {
                    unsigned short pv = (kt < 25) ? f2bf(s[kt][r]) : (unsigned short)0;
                    Pw[(kgrp * 4 + r) * KS + t * 16 + lm] = pv;
                }
            }
            __builtin_amdgcn_wave_barrier();
            __builtin_amdgcn_s_waitcnt(0);
            __builtin_amdgcn_wave_barrier();
            bf16x8 Pf = *(const bf16x8*)(Pw + lm * KS + kgrp * 8);
            bf16x8 Vf = *(const bf16x8*)(Vt + lm * VS + kc * 32 + kgrp * 8);
            O = __builtin_amdgcn_mfma_f32_16x16x32_bf16(Pf, Vf, O, 0, 0, 0);
            __builtin_amdgcn_wave_barrier();
        }
        // O: col=lm=d, row=kgrp*4+r=q_local; normalize and store bf16
#pragma unroll
        for (int r = 0; r < 4; ++r) {
            int q = q0 + kgrp * 4 + r;
            out[((size_t)(b * 400 + q)) * 128 + h * 16 + lm] = f2bf(O[r] * rinv[r]);
        }
    }
}

// ---------------------------------------------------------------------------
extern "C" void kernel_launch(void* const* d_in, const int* in_sizes, int n_in,
                              void* d_out, int out_size, void* d_ws, size_t ws_size,
                              hipStream_t stream) {
    (void)in_sizes; (void)n_in; (void)out_size; (void)ws_size;
    const float* x      = (const float*)d_in[0];
    const float* w_init = (const float*)d_in[1];
    const float* b_init = (const float*)d_in[2];
    const float* lncg   = (const float*)d_in[3];
    const float* lncb   = (const float*)d_in[4];
    const float* w_dw   = (const float*)d_in[5];
    const float* b_dw   = (const float*)d_in[6];
    const float* w_pw   = (const float*)d_in[7];
    const float* b_pw   = (const float*)d_in[8];
    const float* lnag   = (const float*)d_in[9];
    const float* lnab   = (const float*)d_in[10];
    const float* wq     = (const float*)d_in[11];
    const float* bq     = (const float*)d_in[12];
    const float* wk     = (const float*)d_in[13];
    const float* bk     = (const float*)d_in[14];
    const float* wv     = (const float*)d_in[15];
    const float* bv     = (const float*)d_in[16];
    const float* wo     = (const float*)d_in[17];
    const float* bo     = (const float*)d_in[18];
    const float* lnfg   = (const float*)d_in[19];
    const float* lnfb   = (const float*)d_in[20];
    const float* w1     = (const float*)d_in[21];
    const float* b1     = (const float*)d_in[22];
    const float* w2     = (const float*)d_in[23];
    const float* b2     = (const float*)d_in[24];

    float* ws = (float*)d_ws;
    const size_t NBL = (size_t)BL * D;   // 3,276,800
    float* h0 = ws;
    float* outp = (float*)d_out;

    unsigned short* hnb = (unsigned short*)(ws + NBL);
    unsigned short* t0b = hnb + NBL;
    unsigned short* qb  = t0b + NBL;
    unsigned short* kb  = qb + NBL;
    unsigned short* vb  = kb + NBL;
    unsigned short* wt  = vb + NBL;                 // 10*16384 bf16
    unsigned short* xb  = wt + 10 * 16384;          // 64*404*512 bf16
    unsigned short* wbt = xb + (size_t)64 * 404 * 512;

    // pre-passes
    k_cvt_x<<<6464, 256, 0, stream>>>(x, xb);
    k_cvt_w<<<1280, 256, 0, stream>>>(w_init, wbt);
    k_cvt_wall<<<640, 256, 0, stream>>>(
        w_pw, w_pw + 16384, w_pw + 2 * 16384, w_pw + 3 * 16384,
        wq, wk, wv, wo, w1, w2, wt);

    // 1) init conv + posenc
    k_initconv_mfma<<<320, 256, 0, stream>>>(xb, wbt, b_init, h0);

    // 2) 4x depthwise-separable conv blocks (pre-LN, residual)
    for (int i = 0; i < NCONV; ++i) {
        k_ln<<<6400, 256, 0, stream>>>(h0, lncg + i * D, lncb + i * D, hnb);
        k_dw<<<1600, 256, 0, stream>>>(hnb, w_dw + (size_t)i * 7 * D, b_dw + i * D, t0b);
        k_gemm_bf16<<<400, 256, 0, stream>>>(t0b, wt + (size_t)i * 16384,
                                             b_pw + i * D, h0, h0, nullptr, 1, 1.f);
    }

    // 3) attention
    k_ln<<<6400, 256, 0, stream>>>(h0, lnag, lnab, hnb);
    k_gemm_bf16<<<400, 256, 0, stream>>>(hnb, wt + 4 * 16384, bq, nullptr,
                                         nullptr, qb, 0, 0.25f);
    k_gemm_bf16<<<400, 256, 0, stream>>>(hnb, wt + 5 * 16384, bk, nullptr,
                                         nullptr, kb, 0, 1.f);
    k_gemm_bf16<<<400, 256, 0, stream>>>(hnb, wt + 6 * 16384, bv, nullptr,
                                         nullptr, vb, 0, 1.f);
    k_attn_mfma<<<512, 256, 0, stream>>>(qb, kb, vb, t0b);
    k_gemm_bf16<<<400, 256, 0, stream>>>(t0b, wt + 7 * 16384, bo, h0,
                                         h0, nullptr, 0, 1.f);

    // 4) FFN
    k_ln<<<6400, 256, 0, stream>>>(h0, lnfg, lnfb, hnb);
    k_gemm_bf16<<<400, 256, 0, stream>>>(hnb, wt + 8 * 16384, b1, nullptr,
                                         nullptr, t0b, 1, 1.f);
    k_gemm_bf16<<<400, 256, 0, stream>>>(t0b, wt + 9 * 16384, b2, h0,
                                         outp, nullptr, 0, 1.f);
}

// Round 4
// 381.759 us; speedup vs baseline: 2.2903x; 1.3226x over previous
//
#include <hip/hip_runtime.h>
#include <hip/hip_bf16.h>
#include <math.h>

#define B 64
#define L 400
#define IN_DIM 500
#define D 128
#define H 8
#define HD 16
#define NCONV 4
#define BL (B*L)

typedef __attribute__((ext_vector_type(8))) unsigned short ushort8;
typedef __attribute__((ext_vector_type(8))) short bf16x8;
typedef __attribute__((ext_vector_type(4))) float f32x4;

__device__ __forceinline__ unsigned short f2bf(float f) {
    unsigned u = __float_as_uint(f);
    unsigned r = (u + 0x7fffu + ((u >> 16) & 1u)) >> 16;
    return (unsigned short)r;
}
__device__ __forceinline__ float bf2f(unsigned short u) {
    return __uint_as_float(((unsigned)u) << 16);
}

__device__ __forceinline__ void gload16(const void* g, void* l) {
    __builtin_amdgcn_global_load_lds(
        (const __attribute__((address_space(1))) unsigned int*)g,
        (__attribute__((address_space(3))) unsigned int*)l,
        16, 0, 0);
}

// ---------------------------------------------------------------------------
// Pre-pass A: x fp32 [B,400,500] -> bf16 [B,404,512]; 2 zero guard rows.
// ---------------------------------------------------------------------------
__global__ __launch_bounds__(256) void k_cvt_x(
        const float* __restrict__ x, unsigned short* __restrict__ xb) {
    int idx = blockIdx.x * 256 + threadIdx.x;   // chunk of 8 bf16
    int row = idx >> 6, ch = idx & 63;
    int b = row / 404, rr = row - b * 404;
    ushort8 o = (ushort8)0;
    if (rr >= 2 && rr < 402) {
        int l = rr - 2;
        const float* src = x + ((size_t)b * 400 + l) * 500 + ch * 8;
        if (ch < 62) {
            float4 v0 = *(const float4*)(src);
            float4 v1 = *(const float4*)(src + 4);
            o[0] = f2bf(v0.x); o[1] = f2bf(v0.y); o[2] = f2bf(v0.z); o[3] = f2bf(v0.w);
            o[4] = f2bf(v1.x); o[5] = f2bf(v1.y); o[6] = f2bf(v1.z); o[7] = f2bf(v1.w);
        } else {
#pragma unroll
            for (int j = 0; j < 8; ++j) {
                int c = ch * 8 + j;
                o[j] = (c < 500) ? f2bf(src[j]) : (unsigned short)0;
            }
        }
    }
    *(ushort8*)(xb + (size_t)idx * 8) = o;
}

// ---------------------------------------------------------------------------
// Pre-pass B: w_init fp32 [5,500,128] -> bf16 transposed+padded [5,128,512].
// ---------------------------------------------------------------------------
__global__ __launch_bounds__(256) void k_cvt_w(
        const float* __restrict__ w, unsigned short* __restrict__ wbt) {
    int idx = blockIdx.x * 256 + threadIdx.x;
    int k = idx & 511, n = (idx >> 9) & 127, t = idx >> 16;
    float v = (k < 500) ? w[((size_t)t * 500 + k) * 128 + n] : 0.f;
    wbt[idx] = f2bf(v);
}

// ---------------------------------------------------------------------------
// Pre-pass C: 10 [128,128] fp32 weights -> bf16 transposed wt[n][k].
// ---------------------------------------------------------------------------
__global__ __launch_bounds__(256) void k_cvt_wall(
        const float* w0, const float* w1, const float* w2, const float* w3,
        const float* w4, const float* w5, const float* w6, const float* w7,
        const float* w8, const float* w9, unsigned short* __restrict__ out) {
    const float* arr[10] = {w0,w1,w2,w3,w4,w5,w6,w7,w8,w9};
    int widx = blockIdx.x >> 6;
    const float* w = arr[widx];
    int idx = ((blockIdx.x & 63) << 8) + threadIdx.x;
    int n = idx >> 7, k = idx & 127;
    out[(size_t)widx * 16384 + idx] = f2bf(w[k * 128 + n]);
}

// ---------------------------------------------------------------------------
// Kernel 1 v2: init conv MFMA, N-split for occupancy.
// Grid 640 = b(64) x ltile(5) x nhalf(2). Tile 80m x 64n, BK=64.
// LDS 18 KB -> multiple blocks/CU; latency hidden by cross-block waves.
// Each wave: 5 m-frags x 1 n-frag(16).
// ---------------------------------------------------------------------------
#define TM 80
#define BK 64
__global__ __launch_bounds__(256) void k_initconv_mfma(
        const unsigned short* __restrict__ xb,
        const unsigned short* __restrict__ wbt,
        const float* __restrict__ bias, float* __restrict__ out) {
    __shared__ unsigned short As[TM * BK];   // 10 KB
    __shared__ unsigned short Ws[64 * BK];   // 8 KB
    int tid = threadIdx.x;
    int b = blockIdx.x / 10;
    int rem = blockIdx.x - b * 10;
    int l0 = (rem >> 1) * TM;
    int nh = rem & 1;
    int lane = tid & 63, wave = tid >> 6;
    int kgrp = lane >> 4, lm = lane & 15;

    f32x4 acc[5];
#pragma unroll
    for (int mf = 0; mf < 5; ++mf) acc[mf] = (f32x4)0.f;

    for (int t = 0; t < 5; ++t) {
        const unsigned short* arow = xb + ((size_t)(b * 404 + l0 + t)) * 512;
        const unsigned short* wrow = wbt + (size_t)t * 128 * 512 + (size_t)nh * 64 * 512;
        for (int k0 = 0; k0 < 512; k0 += BK) {
            // stage A: 640 16B chunks, swizzled
            {
                int idx = tid;
#pragma unroll
                for (int i = 0; i < 2; ++i) {
                    int r = idx >> 3, sc = idx & 7;
                    gload16(arow + (size_t)r * 512 + k0 + ((sc ^ (r & 7)) * 8),
                            As + idx * 8);
                    idx += 256;
                }
                if (idx < 640) {
                    int r = idx >> 3, sc = idx & 7;
                    gload16(arow + (size_t)r * 512 + k0 + ((sc ^ (r & 7)) * 8),
                            As + idx * 8);
                }
            }
            // stage W: 512 chunks
#pragma unroll
            for (int i = 0; i < 2; ++i) {
                int idx = tid + i * 256;
                int n = idx >> 3, sc = idx & 7;
                gload16(wrow + (size_t)n * 512 + k0 + ((sc ^ (n & 7)) * 8),
                        Ws + idx * 8);
            }
            __syncthreads();
#pragma unroll
            for (int ks = 0; ks < 2; ++ks) {
                int gc = ks * 4 + kgrp;
                int n = wave * 16 + lm;
                bf16x8 bfr = *(const bf16x8*)(Ws + n * 64 + ((gc ^ (n & 7)) * 8));
#pragma unroll
                for (int mf = 0; mf < 5; ++mf) {
                    int r = mf * 16 + lm;
                    bf16x8 af = *(const bf16x8*)(As + r * 64 + ((gc ^ (r & 7)) * 8));
                    acc[mf] = __builtin_amdgcn_mfma_f32_16x16x32_bf16(
                        af, bfr, acc[mf], 0, 0, 0);
                }
            }
            __syncthreads();
        }
    }

    // epilogue: + bias + posenc; C/D: col=lm, row=kgrp*4+r
    {
        int n = nh * 64 + wave * 16 + lm;
        float bs = bias[n];
        float pbase = expf(-(float)(n & ~1) * (9.210340371976184f / 128.0f));
#pragma unroll
        for (int mf = 0; mf < 5; ++mf) {
#pragma unroll
            for (int r = 0; r < 4; ++r) {
                int l = l0 + mf * 16 + kgrp * 4 + r;
                float ang = (float)l * pbase;
                float pe = (n & 1) ? cosf(ang) : sinf(ang);
                out[((size_t)b * 400 + l) * 128 + n] = acc[mf][r] + bs + pe;
            }
        }
    }
}

// ---------------------------------------------------------------------------
// Kernel 2: LayerNorm fp32 in -> bf16 out.
// ---------------------------------------------------------------------------
__global__ __launch_bounds__(256) void k_ln(
        const float* __restrict__ in, const float* __restrict__ g,
        const float* __restrict__ bta, unsigned short* __restrict__ out) {
    int wave = threadIdx.x >> 6, lane = threadIdx.x & 63;
    size_t row = (size_t)blockIdx.x * 4 + wave;
    const float* p = in + row * D;
    float2 v = *(const float2*)(p + lane * 2);
    float s = v.x + v.y;
    float q = v.x * v.x + v.y * v.y;
#pragma unroll
    for (int off = 32; off; off >>= 1) {
        s += __shfl_xor(s, off);
        q += __shfl_xor(q, off);
    }
    float mu  = s * (1.f / 128.f);
    float var = q * (1.f / 128.f) - mu * mu;
    float inv = rsqrtf(var + 1e-5f);
    float2 gg = *(const float2*)(g + lane * 2);
    float2 bb = *(const float2*)(bta + lane * 2);
    float ox = (v.x - mu) * inv * gg.x + bb.x;
    float oy = (v.y - mu) * inv * gg.y + bb.y;
    unsigned pk = (unsigned)f2bf(ox) | ((unsigned)f2bf(oy) << 16);
    *(unsigned*)(out + row * D + lane * 2) = pk;
}

// ---------------------------------------------------------------------------
// Kernel 3: depthwise conv k=7 pad=3 + bias, bf16 in/out.
// ---------------------------------------------------------------------------
__global__ __launch_bounds__(256) void k_dw(
        const unsigned short* __restrict__ in, const float* __restrict__ w,
        const float* __restrict__ bias, unsigned short* __restrict__ out) {
    __shared__ float s[22 * D];
    int tid = threadIdx.x;
    int b  = blockIdx.x / 25;
    int l0 = (blockIdx.x - b * 25) * 16;
    for (int idx = tid; idx < 22 * 16; idx += 256) {
        int r = idx >> 4, c = idx & 15;
        int gl = l0 - 3 + r;
        float vals[8];
        if (gl >= 0 && gl < L) {
            ushort8 u = *(const ushort8*)(in + ((size_t)b * L + gl) * D + c * 8);
#pragma unroll
            for (int j = 0; j < 8; ++j) vals[j] = bf2f(u[j]);
        } else {
#pragma unroll
            for (int j = 0; j < 8; ++j) vals[j] = 0.f;
        }
#pragma unroll
        for (int j = 0; j < 8; ++j) s[r * D + c * 8 + j] = vals[j];
    }
    __syncthreads();
    int d = tid & 127, half = tid >> 7;
    float wr[7];
#pragma unroll
    for (int t = 0; t < 7; ++t) wr[t] = w[t * D + d];
    float bs = bias[d];
    for (int jj = 0; jj < 8; ++jj) {
        int lj = half * 8 + jj;
        float a = bs;
#pragma unroll
        for (int t = 0; t < 7; ++t) a = fmaf(s[(lj + t) * D + d], wr[t], a);
        out[((size_t)b * L + l0 + lj) * D + d] = f2bf(a);
    }
}

// ---------------------------------------------------------------------------
// Kernel 4 v2: bf16 MFMA GEMM, 32m x 128n tiles, grid 800 for occupancy.
// 4 waves in 2m x 2n grid; wave owns 16m x 64n (4 frags).
// ---------------------------------------------------------------------------
__global__ __launch_bounds__(256) void k_gemm_bf16(
        const unsigned short* __restrict__ A,
        const unsigned short* __restrict__ Wt,
        const float* __restrict__ bias,
        const float* __restrict__ res,
        float* __restrict__ outf,
        unsigned short* __restrict__ outb,
        int relu, float oscale) {
    __shared__ unsigned short As[32 * 128];   // 8 KB
    __shared__ unsigned short Ws[128 * 128];  // 32 KB
    int tid = threadIdx.x;
    int m0 = blockIdx.x * 32;
    int lane = tid & 63, wave = tid >> 6;
    int lm = lane & 15, kgrp = lane >> 4;
    int wm = wave >> 1, wn = wave & 1;

#pragma unroll
    for (int i = 0; i < 2; ++i) {
        int idx = tid + i * 256;
        int r = idx >> 4, sc = idx & 15;
        gload16(A + ((size_t)(m0 + r)) * 128 + ((sc ^ (r & 15)) * 8), As + idx * 8);
    }
#pragma unroll
    for (int i = 0; i < 8; ++i) {
        int idx = tid + i * 256;
        int n = idx >> 4, sc = idx & 15;
        gload16(Wt + ((size_t)n) * 128 + ((sc ^ (n & 15)) * 8), Ws + idx * 8);
    }
    __syncthreads();

    f32x4 acc[4];
#pragma unroll
    for (int nt = 0; nt < 4; ++nt) acc[nt] = (f32x4)0.f;

#pragma unroll
    for (int kc = 0; kc < 4; ++kc) {
        int c = kc * 4 + kgrp;
        int r = wm * 16 + lm;
        bf16x8 af = *(const bf16x8*)(As + (r * 16 + (c ^ (r & 15))) * 8);
#pragma unroll
        for (int nt = 0; nt < 4; ++nt) {
            int n = wn * 64 + nt * 16 + lm;
            bf16x8 bfv = *(const bf16x8*)(Ws + (n * 16 + (c ^ (n & 15))) * 8);
            acc[nt] = __builtin_amdgcn_mfma_f32_16x16x32_bf16(af, bfv, acc[nt], 0, 0, 0);
        }
    }

#pragma unroll
    for (int nt = 0; nt < 4; ++nt) {
        int n = wn * 64 + nt * 16 + lm;
        float bs = bias[n];
#pragma unroll
        for (int r = 0; r < 4; ++r) {
            size_t m = (size_t)m0 + wm * 16 + kgrp * 4 + r;
            float v = acc[nt][r] + bs;
            if (relu) v = fmaxf(v, 0.f);
            if (res)  v += res[m * 128 + n];
            if (outf) outf[m * 128 + n] = v;
            else      outb[m * 128 + n] = f2bf(v * oscale);
        }
    }
}

// ---------------------------------------------------------------------------
// Kernel 5: MFMA attention (unchanged from R3).
// ---------------------------------------------------------------------------
#define KS 40
#define VS 424
__global__ __launch_bounds__(256) void k_attn_mfma(
        const unsigned short* __restrict__ qb,
        const unsigned short* __restrict__ kb,
        const unsigned short* __restrict__ vb,
        unsigned short* __restrict__ out) {
    __shared__ __align__(16) unsigned short Kpad[400 * KS];
    __shared__ __align__(16) unsigned short Vt[16 * VS];
    __shared__ __align__(16) unsigned short Ptmp[4][16 * KS];
    int tid = threadIdx.x;
    int b = blockIdx.x >> 3, h = blockIdx.x & 7;
    int lane = tid & 63, wave = tid >> 6;
    int lm = lane & 15, kgrp = lane >> 4;

    for (int idx = tid; idx < 800; idx += 256) {
        int l = idx >> 1, half = idx & 1;
        ushort8 kv = *(const ushort8*)(kb + ((size_t)(b * 400 + l)) * 128 + h * 16 + half * 8);
        *(ushort8*)(Kpad + l * KS + half * 8) = kv;
        *(ushort8*)(Kpad + l * KS + 16 + half * 8) = (ushort8)0;
    }
    for (int idx = tid; idx < 800; idx += 256) {
        int kk = idx >> 1, dh = idx & 1;
        ushort8 vv = *(const ushort8*)(vb + ((size_t)(b * 400 + kk)) * 128 + h * 16 + dh * 8);
#pragma unroll
        for (int j = 0; j < 8; ++j) Vt[(dh * 8 + j) * VS + kk] = vv[j];
    }
    {
        int d = tid >> 4, kk = 400 + (tid & 15);
        Vt[d * VS + kk] = 0;
    }
    __syncthreads();

    unsigned short* Pw = Ptmp[wave];
    for (int tt = wave; tt < 25; tt += 4) {
        int q0 = tt * 16;
        bf16x8 Qf = *(const bf16x8*)(qb + ((size_t)(b * 400 + q0 + lm)) * 128 + h * 16 + kgrp * 8);
        f32x4 s[25];
#pragma unroll
        for (int kt = 0; kt < 25; ++kt) {
            bf16x8 Kf = *(const bf16x8*)(Kpad + (kt * 16 + lm) * KS + kgrp * 8);
            s[kt] = __builtin_amdgcn_mfma_f32_16x16x32_bf16(Qf, Kf, (f32x4)0.f, 0, 0, 0);
        }
        float rmax[4], rsum[4];
#pragma unroll
        for (int r = 0; r < 4; ++r) rmax[r] = -1e30f;
#pragma unroll
        for (int kt = 0; kt < 25; ++kt)
#pragma unroll
            for (int r = 0; r < 4; ++r) rmax[r] = fmaxf(rmax[r], s[kt][r]);
#pragma unroll
        for (int mask = 1; mask <= 8; mask <<= 1)
#pragma unroll
            for (int r = 0; r < 4; ++r) rmax[r] = fmaxf(rmax[r], __shfl_xor(rmax[r], mask));
#pragma unroll
        for (int r = 0; r < 4; ++r) rsum[r] = 0.f;
#pragma unroll
        for (int kt = 0; kt < 25; ++kt)
#pragma unroll
            for (int r = 0; r < 4; ++r) {
                float p = __expf(s[kt][r] - rmax[r]);
                s[kt][r] = p;
                rsum[r] += p;
            }
#pragma unroll
        for (int mask = 1; mask <= 8; mask <<= 1)
#pragma unroll
            for (int r = 0; r < 4; ++r) rsum[r] += __shfl_xor(rsum[r], mask);
        float rinv[4];
#pragma unroll
        for (int r = 0; r < 4; ++r) rinv[r] = 1.f / rsum[r];

        f32x4 O = (f32x4)0.f;
#pragma unroll
        for (int kc = 0; kc < 13; ++kc) {
#pragma unroll
            for (int t = 0; t < 2; ++t) {
                int kt = kc * 2 + t;
#pragma unroll
                for (int r = 0; r < 4; ++r) {
                    unsigned short pv = (kt < 25) ? f2bf(s[kt][r]) : (unsigned short)0;
                    Pw[(kgrp * 4 + r) * KS + t * 16 + lm] = pv;
                }
            }
            __builtin_amdgcn_wave_barrier();
            __builtin_amdgcn_s_waitcnt(0);
            __builtin_amdgcn_wave_barrier();
            bf16x8 Pf = *(const bf16x8*)(Pw + lm * KS + kgrp * 8);
            bf16x8 Vf = *(const bf16x8*)(Vt + lm * VS + kc * 32 + kgrp * 8);
            O = __builtin_amdgcn_mfma_f32_16x16x32_bf16(Pf, Vf, O, 0, 0, 0);
            __builtin_amdgcn_wave_barrier();
        }
#pragma unroll
        for (int r = 0; r < 4; ++r) {
            int q = q0 + kgrp * 4 + r;
            out[((size_t)(b * 400 + q)) * 128 + h * 16 + lm] = f2bf(O[r] * rinv[r]);
        }
    }
}

// ---------------------------------------------------------------------------
extern "C" void kernel_launch(void* const* d_in, const int* in_sizes, int n_in,
                              void* d_out, int out_size, void* d_ws, size_t ws_size,
                              hipStream_t stream) {
    (void)in_sizes; (void)n_in; (void)out_size; (void)ws_size;
    const float* x      = (const float*)d_in[0];
    const float* w_init = (const float*)d_in[1];
    const float* b_init = (const float*)d_in[2];
    const float* lncg   = (const float*)d_in[3];
    const float* lncb   = (const float*)d_in[4];
    const float* w_dw   = (const float*)d_in[5];
    const float* b_dw   = (const float*)d_in[6];
    const float* w_pw   = (const float*)d_in[7];
    const float* b_pw   = (const float*)d_in[8];
    const float* lnag   = (const float*)d_in[9];
    const float* lnab   = (const float*)d_in[10];
    const float* wq     = (const float*)d_in[11];
    const float* bq     = (const float*)d_in[12];
    const float* wk     = (const float*)d_in[13];
    const float* bk     = (const float*)d_in[14];
    const float* wv     = (const float*)d_in[15];
    const float* bv     = (const float*)d_in[16];
    const float* wo     = (const float*)d_in[17];
    const float* bo     = (const float*)d_in[18];
    const float* lnfg   = (const float*)d_in[19];
    const float* lnfb   = (const float*)d_in[20];
    const float* w1     = (const float*)d_in[21];
    const float* b1     = (const float*)d_in[22];
    const float* w2     = (const float*)d_in[23];
    const float* b2     = (const float*)d_in[24];

    float* ws = (float*)d_ws;
    const size_t NBL = (size_t)BL * D;
    float* h0 = ws;
    float* outp = (float*)d_out;

    unsigned short* hnb = (unsigned short*)(ws + NBL);
    unsigned short* t0b = hnb + NBL;
    unsigned short* qb  = t0b + NBL;
    unsigned short* kb  = qb + NBL;
    unsigned short* vb  = kb + NBL;
    unsigned short* wt  = vb + NBL;
    unsigned short* xb  = wt + 10 * 16384;
    unsigned short* wbt = xb + (size_t)64 * 404 * 512;

    // pre-passes
    k_cvt_x<<<6464, 256, 0, stream>>>(x, xb);
    k_cvt_w<<<1280, 256, 0, stream>>>(w_init, wbt);
    k_cvt_wall<<<640, 256, 0, stream>>>(
        w_pw, w_pw + 16384, w_pw + 2 * 16384, w_pw + 3 * 16384,
        wq, wk, wv, wo, w1, w2, wt);

    // 1) init conv + posenc
    k_initconv_mfma<<<640, 256, 0, stream>>>(xb, wbt, b_init, h0);

    // 2) 4x depthwise-separable conv blocks (pre-LN, residual)
    for (int i = 0; i < NCONV; ++i) {
        k_ln<<<6400, 256, 0, stream>>>(h0, lncg + i * D, lncb + i * D, hnb);
        k_dw<<<1600, 256, 0, stream>>>(hnb, w_dw + (size_t)i * 7 * D, b_dw + i * D, t0b);
        k_gemm_bf16<<<800, 256, 0, stream>>>(t0b, wt + (size_t)i * 16384,
                                             b_pw + i * D, h0, h0, nullptr, 1, 1.f);
    }

    // 3) attention
    k_ln<<<6400, 256, 0, stream>>>(h0, lnag, lnab, hnb);
    k_gemm_bf16<<<800, 256, 0, stream>>>(hnb, wt + 4 * 16384, bq, nullptr,
                                         nullptr, qb, 0, 0.25f);
    k_gemm_bf16<<<800, 256, 0, stream>>>(hnb, wt + 5 * 16384, bk, nullptr,
                                         nullptr, kb, 0, 1.f);
    k_gemm_bf16<<<800, 256, 0, stream>>>(hnb, wt + 6 * 16384, bv, nullptr,
                                         nullptr, vb, 0, 1.f);
    k_attn_mfma<<<512, 256, 0, stream>>>(qb, kb, vb, t0b);
    k_gemm_bf16<<<800, 256, 0, stream>>>(t0b, wt + 7 * 16384, bo, h0,
                                         h0, nullptr, 0, 1.f);

    // 4) FFN
    k_ln<<<6400, 256, 0, stream>>>(h0, lnfg, lnfb, hnb);
    k_gemm_bf16<<<800, 256, 0, stream>>>(hnb, wt + 8 * 16384, b1, nullptr,
                                         nullptr, t0b, 1, 1.f);
    k_gemm_bf16<<<800, 256, 0, stream>>>(t0b, wt + 9 * 16384, b2, h0,
                                         outp, nullptr, 0, 1.f);
}